// Round 16
// baseline (128.740 us; speedup 1.0000x reference)
//
#include <hip/hip_runtime.h>

// Problem constants: B=4, N=512, M=512, D=128, H=256, DOUT=128
#define BB    4
#define NN    512
#define MM    512
#define DD    128
#define HH    256
#define DOUTC 128

typedef float v2f __attribute__((ext_vector_type(2)));
typedef float v4f __attribute__((ext_vector_type(4)));

// ---------------------------------------------------------------------------
// Kernel 1: precompute (258 blocks x 1024 threads) — VERIFIED r15 body.
// Blocks 0..255: A/C rows. Blocks 256..257: SAT[b][h] = (sum_m Y[b,m])·W1col.
// ---------------------------------------------------------------------------
__global__ __launch_bounds__(1024) void precompute_ac(
    const float* __restrict__ X, const float* __restrict__ Y,
    const float* __restrict__ W1, const float* __restrict__ b1,
    float* __restrict__ AC, float* __restrict__ SAT)
{
    __shared__ __align__(16) float rows[16][DD];     // 8 KB
    __shared__ __align__(16) v4f mrg[3][4][4][64];   // 48 KB
    const int bid = blockIdx.x;
    const int t   = threadIdx.x;

    if (bid < 256) {
        const int isC = bid >> 7;
        const int r0  = (bid & 127) * 16;
        const float* src = isC ? X : Y;

        if (t < 512)
            reinterpret_cast<v4f*>(&rows[0][0])[t] =
                reinterpret_cast<const v4f*>(src + (size_t)r0 * DD)[t];
        __syncthreads();

        const int hq = t & 63;
        const int dq = (t >> 6) & 3;
        const int rs = t >> 8;
        const int d0 = dq * 32;
        const float* wp = W1 + (isC ? DD * HH : 0) + hq * 4;

        v4f acc[4];
#pragma unroll
        for (int r = 0; r < 4; ++r) acc[r] = (v4f){0.f, 0.f, 0.f, 0.f};

#pragma unroll 2
        for (int dg = 0; dg < 32; dg += 4) {
            const int d = d0 + dg;
            const v4f w0 = *reinterpret_cast<const v4f*>(&wp[(d + 0) * HH]);
            const v4f w1 = *reinterpret_cast<const v4f*>(&wp[(d + 1) * HH]);
            const v4f w2 = *reinterpret_cast<const v4f*>(&wp[(d + 2) * HH]);
            const v4f w3 = *reinterpret_cast<const v4f*>(&wp[(d + 3) * HH]);
#pragma unroll
            for (int r = 0; r < 4; ++r) {
                const v4f rv = *reinterpret_cast<const v4f*>(&rows[rs * 4 + r][d]);
                acc[r] += w0 * rv.x;
                acc[r] += w1 * rv.y;
                acc[r] += w2 * rv.z;
                acc[r] += w3 * rv.w;
            }
        }

        if (dq > 0) {
#pragma unroll
            for (int r = 0; r < 4; ++r) mrg[dq - 1][rs][r][hq] = acc[r];
        }
        __syncthreads();
        if (dq == 0) {
#pragma unroll
            for (int r = 0; r < 4; ++r) {
#pragma unroll
                for (int p = 0; p < 3; ++p) acc[r] += mrg[p][rs][r][hq];
            }
            v4f bias = (v4f){0.f, 0.f, 0.f, 0.f};
            if (isC) bias = *reinterpret_cast<const v4f*>(&b1[hq * 4]);
#pragma unroll
            for (int r = 0; r < 4; ++r)
                *reinterpret_cast<v4f*>(
                    &AC[((size_t)(isC * 2048 + r0 + rs * 4 + r)) * HH + hq * 4]) =
                    acc[r] + bias;
        }
    } else {
        const int half = t >> 9;
        const int bb   = (bid - 256) * 2 + half;
        const int tt   = t & 511;
        float* scr = &rows[0][0];

        const int d  = tt & 127;
        const int mq = tt >> 7;
        const float* yp = Y + ((size_t)(bb * MM + mq * 128)) * DD + d;
        float s = 0.f;
#pragma unroll 4
        for (int i = 0; i < 128; ++i) s += yp[(size_t)i * DD];
        scr[half * 512 + mq * 128 + d] = s;
        __syncthreads();

        if (tt < 256) {
            const float* base = scr + half * 512;
            float sat = 0.f;
#pragma unroll 4
            for (int dd = 0; dd < 128; ++dd) {
                const float ys = base[dd] + base[128 + dd] +
                                 base[256 + dd] + base[384 + dd];
                sat = fmaf(ys, W1[dd * HH + tt], sat);
            }
            SAT[bb * HH + tt] = sat;
        }
    }
}

// ---------------------------------------------------------------------------
// Kernel 2 (templated): abs-sum main loop + ablation variants.
// MODE 0 = FULL (staggered m-start, writes part)  — the real computation
// MODE 1 = LOADONLY (A loads + asm sink, lockstep addresses)
// MODE 2 = LOADSTAG (A loads + asm sink, staggered addresses)
// MODE 3 = VALUONLY (synthetic a, full VALU chain + asm sink, no A loads)
// Diagnostics isolate which phase owns the ~35 us wall (7 variants pinned).
// ---------------------------------------------------------------------------
template<int MODE, int REPS>
__global__ __launch_bounds__(256) void abs_main_t(
    const float* __restrict__ A, const float* __restrict__ C,
    float* __restrict__ part)
{
    __shared__ __align__(16) v4f mergeA[3][8][64];   // 24 KB
    const int bid = blockIdx.x;
    const int mc  = bid & 3;
    const int nt  = (bid >> 2) & 63;
    const int b   = bid >> 8;
    const int t   = threadIdx.x;
    const int l   = t & 63;
    const int w   = t >> 6;
    const int h0  = l * 4;
    const int n0  = nt * 8;
    const int start = (nt * 5) & 31;   // de-lockstep rotation (per-block)

    const float* Ab = A + ((size_t)(b * MM + mc * 128 + w * 32)) * HH + h0;

    if (MODE == 1 || MODE == 2) {
        for (int rep = 0; rep < REPS; ++rep) {
#pragma unroll 4
            for (int i = 0; i < 32; ++i) {
                const int ii = (MODE == 2) ? ((i + start) & 31) : i;
                const v4f a = *reinterpret_cast<const v4f*>(&Ab[(size_t)ii * HH]);
                asm volatile("" :: "v"(a.x), "v"(a.y), "v"(a.z), "v"(a.w));
            }
        }
        return;
    }

    const float* Cb = C + ((size_t)(b * NN + n0)) * HH + h0;
    v2f c01[8], c23[8];
#pragma unroll
    for (int j = 0; j < 8; ++j) {
        const v4f cv = *reinterpret_cast<const v4f*>(&Cb[(size_t)j * HH]);
        c01[j] = (v2f){cv.x, cv.y};
        c23[j] = (v2f){cv.z, cv.w};
    }

    float acc[8][4];
#pragma unroll
    for (int j = 0; j < 8; ++j)
#pragma unroll
        for (int u = 0; u < 4; ++u) acc[j][u] = 0.f;

    for (int rep = 0; rep < REPS; ++rep) {
#pragma unroll 4
        for (int i = 0; i < 32; ++i) {
            v2f a01, a23;
            if (MODE == 3) {
                const float fi = (float)(i + rep);
                a01 = (v2f){fi, fi + 0.25f};
                a23 = (v2f){fi + 0.5f, fi + 0.75f};
            } else {
                const int ii = (i + start) & 31;
                const v4f a = *reinterpret_cast<const v4f*>(&Ab[(size_t)ii * HH]);
                a01 = (v2f){a.x, a.y};
                a23 = (v2f){a.z, a.w};
            }
#pragma unroll
            for (int j = 0; j < 8; ++j) {
                const v2f s01 = a01 + c01[j];      // v_pk_add_f32
                const v2f s23 = a23 + c23[j];      // v_pk_add_f32
                acc[j][0] += fabsf(s01.x);         // v_add_f32 acc, |s|, acc
                acc[j][1] += fabsf(s01.y);
                acc[j][2] += fabsf(s23.x);
                acc[j][3] += fabsf(s23.y);
            }
        }
    }

    if (MODE == 3) {
#pragma unroll
        for (int j = 0; j < 8; ++j)
            asm volatile("" :: "v"(acc[j][0]), "v"(acc[j][1]),
                              "v"(acc[j][2]), "v"(acc[j][3]));
        return;
    }

    if (w > 0) {
#pragma unroll
        for (int j = 0; j < 8; ++j)
            mergeA[w - 1][j][l] = (v4f){acc[j][0], acc[j][1], acc[j][2], acc[j][3]};
    }
    __syncthreads();
    if (w == 0) {
#pragma unroll
        for (int j = 0; j < 8; ++j) {
            v4f s = (v4f){acc[j][0], acc[j][1], acc[j][2], acc[j][3]};
#pragma unroll
            for (int p = 0; p < 3; ++p) s += mergeA[p][j][l];
            *reinterpret_cast<v4f*>(&part[((size_t)bid * 8 + j) * HH + h0]) = s;
        }
    }
}

// ---------------------------------------------------------------------------
// Kernel 3: epilogue (512 blocks x 512 threads) — VERIFIED r15 body.
// ---------------------------------------------------------------------------
__global__ __launch_bounds__(512) void epilogue(
    const float* __restrict__ part, const float* __restrict__ SAT,
    const float* __restrict__ C, const float* __restrict__ W2,
    const float* __restrict__ b2, float* __restrict__ out)
{
    __shared__ __align__(16) float Sl[4][HH];   // 4 KB
    __shared__ __align__(16) v4f red[3 * 128];  // 6 KB
    const int bn0 = blockIdx.x * 4;
    const int b   = bn0 >> 9;
    const int t   = threadIdx.x;

    if (t < 256) {
        const int h    = t;
        const float sv = SAT[b * HH + h];
        const int nt   = (bn0 & 511) >> 3;
#pragma unroll
        for (int r = 0; r < 4; ++r) {
            const int bn = bn0 + r;
            const int j  = bn & 7;
            float ab = 0.f;
#pragma unroll
            for (int mcq = 0; mcq < 4; ++mcq)
                ab += part[((size_t)((b * 256 + nt * 4 + mcq)) * 8 + j) * HH + h];
            const float cv = C[(size_t)bn * HH + h];
            Sl[r][h] = 0.5f * (sv + 512.f * cv + ab);
        }
    }
    __syncthreads();

    const int o0 = (t & 31) * 4;
    const int r  = (t >> 5) & 3;
    const int kq = t >> 7;
    const int k0 = kq * 64;
    v4f a4 = (v4f){0.f, 0.f, 0.f, 0.f};
    const float* w2p = W2 + o0;
#pragma unroll 4
    for (int k = k0; k < k0 + 64; k += 4) {
        const v4f sv = *reinterpret_cast<const v4f*>(&Sl[r][k]);
        const v4f wA = *reinterpret_cast<const v4f*>(&w2p[(k + 0) * DOUTC]);
        const v4f wB = *reinterpret_cast<const v4f*>(&w2p[(k + 1) * DOUTC]);
        const v4f wC = *reinterpret_cast<const v4f*>(&w2p[(k + 2) * DOUTC]);
        const v4f wD = *reinterpret_cast<const v4f*>(&w2p[(k + 3) * DOUTC]);
        a4 += wA * sv.x;
        a4 += wB * sv.y;
        a4 += wC * sv.z;
        a4 += wD * sv.w;
    }
    if (kq) red[(kq - 1) * 128 + (t & 127)] = a4;
    __syncthreads();
    if (kq == 0) {
#pragma unroll
        for (int p = 0; p < 3; ++p) a4 += red[p * 128 + (t & 127)];
        a4 += 512.f * (*reinterpret_cast<const v4f*>(&b2[o0]));
        *reinterpret_cast<v4f*>(&out[(size_t)(bn0 + r) * DOUTC + o0]) = a4;
    }
}

// ---------------------------------------------------------------------------
extern "C" void kernel_launch(void* const* d_in, const int* in_sizes, int n_in,
                              void* d_out, int out_size, void* d_ws, size_t ws_size,
                              hipStream_t stream) {
    const float* X  = (const float*)d_in[0];
    const float* Y  = (const float*)d_in[1];
    const float* W1 = (const float*)d_in[2];
    const float* b1 = (const float*)d_in[3];
    const float* W2 = (const float*)d_in[4];
    const float* b2 = (const float*)d_in[5];
    float* out = (float*)d_out;

    float* AC   = (float*)d_ws;                       // 4 MB
    float* A    = AC;
    float* Cm   = AC + 2048 * HH;
    float* part = AC + 4096 * HH;                     // 8 MB
    float* SAT  = part + (size_t)1024 * 8 * HH;       // 4 KB

    hipLaunchKernelGGL(precompute_ac, dim3(258), dim3(1024), 0, stream,
                       X, Y, W1, b1, AC, SAT);
    hipLaunchKernelGGL((abs_main_t<0, 1>), dim3(1024), dim3(256), 0, stream,
                       A, Cm, part);                  // FULL (staggered) -> part
    hipLaunchKernelGGL(epilogue, dim3(512), dim3(512), 0, stream,
                       part, SAT, Cm, W2, b2, out);

    // ---- diagnostics (read-only, after output is produced) ----
    hipLaunchKernelGGL((abs_main_t<1, 3>), dim3(1024), dim3(256), 0, stream,
                       A, Cm, part);                  // LOADONLY x3 (lockstep)
    hipLaunchKernelGGL((abs_main_t<2, 3>), dim3(1024), dim3(256), 0, stream,
                       A, Cm, part);                  // LOADSTAG x3 (staggered)
    hipLaunchKernelGGL((abs_main_t<3, 3>), dim3(1024), dim3(256), 0, stream,
                       A, Cm, part);                  // VALUONLY x3
}

// Round 17
// 52.008 us; speedup vs baseline: 2.4754x; 2.4754x over previous
//
#include <hip/hip_runtime.h>

// Problem constants: B=4, N=512, M=512, D=128, H=256, DOUT=128
#define BB    4
#define NN    512
#define MM    512
#define DD    128
#define HH    256
#define DOUTC 128

typedef float v2f __attribute__((ext_vector_type(2)));
typedef float v4f __attribute__((ext_vector_type(4)));

// ---------------------------------------------------------------------------
// Kernel 1: precompute (258 blocks x 1024 threads) — VERIFIED r15/r16 body.
// Blocks 0..255: A/C rows (R=4 register-tiled GEMM, one plain-LDS dq merge).
// Blocks 256..257: SAT[b][h] = (sum_m Y[b,m])·W1col  (linearity).
// ---------------------------------------------------------------------------
__global__ __launch_bounds__(1024) void precompute_ac(
    const float* __restrict__ X, const float* __restrict__ Y,
    const float* __restrict__ W1, const float* __restrict__ b1,
    float* __restrict__ AC, float* __restrict__ SAT)
{
    __shared__ __align__(16) float rows[16][DD];     // 8 KB
    __shared__ __align__(16) v4f mrg[3][4][4][64];   // 48 KB
    const int bid = blockIdx.x;
    const int t   = threadIdx.x;

    if (bid < 256) {
        const int isC = bid >> 7;
        const int r0  = (bid & 127) * 16;
        const float* src = isC ? X : Y;

        if (t < 512)
            reinterpret_cast<v4f*>(&rows[0][0])[t] =
                reinterpret_cast<const v4f*>(src + (size_t)r0 * DD)[t];
        __syncthreads();

        const int hq = t & 63;
        const int dq = (t >> 6) & 3;
        const int rs = t >> 8;
        const int d0 = dq * 32;
        const float* wp = W1 + (isC ? DD * HH : 0) + hq * 4;

        v4f acc[4];
#pragma unroll
        for (int r = 0; r < 4; ++r) acc[r] = (v4f){0.f, 0.f, 0.f, 0.f};

#pragma unroll 2
        for (int dg = 0; dg < 32; dg += 4) {
            const int d = d0 + dg;
            const v4f w0 = *reinterpret_cast<const v4f*>(&wp[(d + 0) * HH]);
            const v4f w1 = *reinterpret_cast<const v4f*>(&wp[(d + 1) * HH]);
            const v4f w2 = *reinterpret_cast<const v4f*>(&wp[(d + 2) * HH]);
            const v4f w3 = *reinterpret_cast<const v4f*>(&wp[(d + 3) * HH]);
#pragma unroll
            for (int r = 0; r < 4; ++r) {
                const v4f rv = *reinterpret_cast<const v4f*>(&rows[rs * 4 + r][d]);
                acc[r] += w0 * rv.x;
                acc[r] += w1 * rv.y;
                acc[r] += w2 * rv.z;
                acc[r] += w3 * rv.w;
            }
        }

        if (dq > 0) {
#pragma unroll
            for (int r = 0; r < 4; ++r) mrg[dq - 1][rs][r][hq] = acc[r];
        }
        __syncthreads();
        if (dq == 0) {
#pragma unroll
            for (int r = 0; r < 4; ++r) {
#pragma unroll
                for (int p = 0; p < 3; ++p) acc[r] += mrg[p][rs][r][hq];
            }
            v4f bias = (v4f){0.f, 0.f, 0.f, 0.f};
            if (isC) bias = *reinterpret_cast<const v4f*>(&b1[hq * 4]);
#pragma unroll
            for (int r = 0; r < 4; ++r)
                *reinterpret_cast<v4f*>(
                    &AC[((size_t)(isC * 2048 + r0 + rs * 4 + r)) * HH + hq * 4]) =
                    acc[r] + bias;
        }
    } else {
        const int half = t >> 9;
        const int bb   = (bid - 256) * 2 + half;
        const int tt   = t & 511;
        float* scr = &rows[0][0];

        const int d  = tt & 127;
        const int mq = tt >> 7;
        const float* yp = Y + ((size_t)(bb * MM + mq * 128)) * DD + d;
        float s = 0.f;
#pragma unroll 4
        for (int i = 0; i < 128; ++i) s += yp[(size_t)i * DD];
        scr[half * 512 + mq * 128 + d] = s;
        __syncthreads();

        if (tt < 256) {
            const float* base = scr + half * 512;
            float sat = 0.f;
#pragma unroll 4
            for (int dd = 0; dd < 128; ++dd) {
                const float ys = base[dd] + base[128 + dd] +
                                 base[256 + dd] + base[384 + dd];
                sat = fmaf(ys, W1[dd * HH + tt], sat);
            }
            SAT[bb * HH + tt] = sat;
        }
    }
}

// ---------------------------------------------------------------------------
// Kernel 2: abs-sum main loop (1024 blocks x 256 threads, 4 blocks/CU).
// ROUND-16 ABLATION RESULT: lockstep A-address streams across the 64 blocks
// sharing a (b,mc) region serialize on L2 (pure loads: 17.8 us/rep lockstep
// vs ~BW-bound staggered); VALU chain alone = 5.2 us/rep (= model floor).
// FIX (kept from r16 MODE 0): per-block rotated m-start de-correlates the
// streams. Stagger key mixes nt AND mc for maximum diversity.
// Inner loop: 2 v_pk_add_f32 + 4 abs-fold v_add_f32 per (m, 4h x 1n) = 1.5
// VALU/elem (sat removed via SAT linearity).
// ---------------------------------------------------------------------------
__global__ __launch_bounds__(256) void abs_main(
    const float* __restrict__ A, const float* __restrict__ C,
    float* __restrict__ part)
{
    __shared__ __align__(16) v4f mergeA[3][8][64];   // 24 KB
    const int bid = blockIdx.x;
    const int mc  = bid & 3;
    const int nt  = (bid >> 2) & 63;
    const int b   = bid >> 8;
    const int t   = threadIdx.x;
    const int l   = t & 63;
    const int w   = t >> 6;            // wave: 32 m each
    const int h0  = l * 4;
    const int n0  = nt * 8;
    const int start = (nt * 5 + mc * 9) & 31;   // de-lockstep rotation

    const float* Cb = C + ((size_t)(b * NN + n0)) * HH + h0;
    v2f c01[8], c23[8];
#pragma unroll
    for (int j = 0; j < 8; ++j) {
        const v4f cv = *reinterpret_cast<const v4f*>(&Cb[(size_t)j * HH]);
        c01[j] = (v2f){cv.x, cv.y};
        c23[j] = (v2f){cv.z, cv.w};
    }

    float acc[8][4];
#pragma unroll
    for (int j = 0; j < 8; ++j)
#pragma unroll
        for (int u = 0; u < 4; ++u) acc[j][u] = 0.f;

    const float* Ab = A + ((size_t)(b * MM + mc * 128 + w * 32)) * HH + h0;
#pragma unroll 4
    for (int i = 0; i < 32; ++i) {
        const int ii = (i + start) & 31;
        const v4f a = *reinterpret_cast<const v4f*>(&Ab[(size_t)ii * HH]);
        const v2f a01 = (v2f){a.x, a.y};
        const v2f a23 = (v2f){a.z, a.w};
#pragma unroll
        for (int j = 0; j < 8; ++j) {
            const v2f s01 = a01 + c01[j];      // v_pk_add_f32
            const v2f s23 = a23 + c23[j];      // v_pk_add_f32
            acc[j][0] += fabsf(s01.x);         // v_add_f32 acc, |s|, acc
            acc[j][1] += fabsf(s01.y);
            acc[j][2] += fabsf(s23.x);
            acc[j][3] += fabsf(s23.y);
        }
    }

    if (w > 0) {
#pragma unroll
        for (int j = 0; j < 8; ++j)
            mergeA[w - 1][j][l] = (v4f){acc[j][0], acc[j][1], acc[j][2], acc[j][3]};
    }
    __syncthreads();
    if (w == 0) {
#pragma unroll
        for (int j = 0; j < 8; ++j) {
            v4f s = (v4f){acc[j][0], acc[j][1], acc[j][2], acc[j][3]};
#pragma unroll
            for (int p = 0; p < 3; ++p) s += mergeA[p][j][l];
            *reinterpret_cast<v4f*>(&part[((size_t)bid * 8 + j) * HH + h0]) = s;
        }
    }
}

// ---------------------------------------------------------------------------
// Kernel 3: epilogue (512 blocks x 512 threads) — VERIFIED r15/r16 body.
//   S[r][h] = 0.5*(SAT[b,h] + 512*C[bn,h] + sum_mc part)
//   out[bn,o] = sum_h S*W2 + 512*b2[o]
// ---------------------------------------------------------------------------
__global__ __launch_bounds__(512) void epilogue(
    const float* __restrict__ part, const float* __restrict__ SAT,
    const float* __restrict__ C, const float* __restrict__ W2,
    const float* __restrict__ b2, float* __restrict__ out)
{
    __shared__ __align__(16) float Sl[4][HH];   // 4 KB
    __shared__ __align__(16) v4f red[3 * 128];  // 6 KB
    const int bn0 = blockIdx.x * 4;
    const int b   = bn0 >> 9;
    const int t   = threadIdx.x;

    if (t < 256) {
        const int h    = t;
        const float sv = SAT[b * HH + h];
        const int nt   = (bn0 & 511) >> 3;
#pragma unroll
        for (int r = 0; r < 4; ++r) {
            const int bn = bn0 + r;
            const int j  = bn & 7;
            float ab = 0.f;
#pragma unroll
            for (int mcq = 0; mcq < 4; ++mcq)
                ab += part[((size_t)((b * 256 + nt * 4 + mcq)) * 8 + j) * HH + h];
            const float cv = C[(size_t)bn * HH + h];
            Sl[r][h] = 0.5f * (sv + 512.f * cv + ab);
        }
    }
    __syncthreads();

    const int o0 = (t & 31) * 4;
    const int r  = (t >> 5) & 3;
    const int kq = t >> 7;
    const int k0 = kq * 64;
    v4f a4 = (v4f){0.f, 0.f, 0.f, 0.f};
    const float* w2p = W2 + o0;
#pragma unroll 4
    for (int k = k0; k < k0 + 64; k += 4) {
        const v4f sv = *reinterpret_cast<const v4f*>(&Sl[r][k]);
        const v4f wA = *reinterpret_cast<const v4f*>(&w2p[(k + 0) * DOUTC]);
        const v4f wB = *reinterpret_cast<const v4f*>(&w2p[(k + 1) * DOUTC]);
        const v4f wC = *reinterpret_cast<const v4f*>(&w2p[(k + 2) * DOUTC]);
        const v4f wD = *reinterpret_cast<const v4f*>(&w2p[(k + 3) * DOUTC]);
        a4 += wA * sv.x;
        a4 += wB * sv.y;
        a4 += wC * sv.z;
        a4 += wD * sv.w;
    }
    if (kq) red[(kq - 1) * 128 + (t & 127)] = a4;
    __syncthreads();
    if (kq == 0) {
#pragma unroll
        for (int p = 0; p < 3; ++p) a4 += red[p * 128 + (t & 127)];
        a4 += 512.f * (*reinterpret_cast<const v4f*>(&b2[o0]));
        *reinterpret_cast<v4f*>(&out[(size_t)(bn0 + r) * DOUTC + o0]) = a4;
    }
}

// ---------------------------------------------------------------------------
extern "C" void kernel_launch(void* const* d_in, const int* in_sizes, int n_in,
                              void* d_out, int out_size, void* d_ws, size_t ws_size,
                              hipStream_t stream) {
    const float* X  = (const float*)d_in[0];
    const float* Y  = (const float*)d_in[1];
    const float* W1 = (const float*)d_in[2];
    const float* b1 = (const float*)d_in[3];
    const float* W2 = (const float*)d_in[4];
    const float* b2 = (const float*)d_in[5];
    float* out = (float*)d_out;

    float* AC   = (float*)d_ws;                       // 4 MB
    float* A    = AC;
    float* Cm   = AC + 2048 * HH;
    float* part = AC + 4096 * HH;                     // 8 MB
    float* SAT  = part + (size_t)1024 * 8 * HH;       // 4 KB

    hipLaunchKernelGGL(precompute_ac, dim3(258), dim3(1024), 0, stream,
                       X, Y, W1, b1, AC, SAT);
    hipLaunchKernelGGL(abs_main, dim3(1024), dim3(256), 0, stream,
                       A, Cm, part);
    hipLaunchKernelGGL(epilogue, dim3(512), dim3(512), 0, stream,
                       part, SAT, Cm, W2, b2, out);
}